// Round 4
// baseline (505.487 us; speedup 1.0000x reference)
//
#include <hip/hip_runtime.h>
#include <hip/hip_bf16.h>

#define DIM 2048
#define SEQLEN 2048
#define NHEADS 16
#define HDIM 128
#define NBATCH 2

using short8 = __attribute__((ext_vector_type(8))) short;
using f32x4 = __attribute__((ext_vector_type(4))) float;
using ushort4v = __attribute__((ext_vector_type(4))) unsigned short;

typedef __attribute__((address_space(1))) const void gvoid_t;
typedef __attribute__((address_space(3))) void lvoid_t;

__device__ __forceinline__ void gl_lds16(const void* g, void* l) {
  __builtin_amdgcn_global_load_lds((gvoid_t*)g, (lvoid_t*)l, 16, 0, 0);
}

__device__ __forceinline__ unsigned short f2bf(float f) {
  union { float f; unsigned int u; } v;
  v.f = f;
  unsigned int u = v.u;
  return (unsigned short)((u + 0x7FFFu + ((u >> 16) & 1u)) >> 16);
}

__device__ __forceinline__ f32x4 mfma16(short8 a, short8 b, f32x4 c) {
  return __builtin_amdgcn_mfma_f32_16x16x32_bf16(a, b, c, 0, 0, 0);
}

// ---------------------------------------------------------------- cast fp32->bf16
__global__ __launch_bounds__(256) void cast_all(
    const float4* __restrict__ x,
    const float4* __restrict__ wq, const float4* __restrict__ wk,
    const float4* __restrict__ wv, const float4* __restrict__ wo,
    ushort4v* __restrict__ xb,
    ushort4v* __restrict__ wqb, ushort4v* __restrict__ wkb,
    ushort4v* __restrict__ wvb, ushort4v* __restrict__ wob)
{
  const long NXV = 2097152;   // 8388608/4
  const long NWV = 1048576;   // 4194304/4
  long tid = (long)blockIdx.x * blockDim.x + threadIdx.x;
  long nth = (long)gridDim.x * blockDim.x;
  for (long i = tid; i < NXV + 4 * NWV; i += nth) {
    const float4* s; ushort4v* dst; long off;
    if (i < NXV) { s = x; dst = xb; off = i; }
    else {
      long j = i - NXV;
      int w = (int)(j >> 20);
      off = j & (NWV - 1);
      switch (w) {
        case 0:  s = wq; dst = wqb; break;
        case 1:  s = wk; dst = wkb; break;
        case 2:  s = wv; dst = wvb; break;
        default: s = wo; dst = wob; break;
      }
    }
    float4 f = s[off];
    ushort4v u;
    u.x = f2bf(f.x); u.y = f2bf(f.y); u.z = f2bf(f.z); u.w = f2bf(f.w);
    dst[off] = u;
  }
}

// ---------------------------------------------------------------- rope cos/sin tables [S][64]
__global__ __launch_bounds__(256) void rope_tables(float* __restrict__ ctab,
                                                   float* __restrict__ stab)
{
  int idx = blockIdx.x * 256 + threadIdx.x;
  if (idx >= SEQLEN * 64) return;
  int s = idx >> 6, i = idx & 63;
  float inv = powf(10000.0f, -(float)(2 * i) * (1.0f / 128.0f));
  float a = (float)s * inv;
  ctab[idx] = cosf(a);
  stab[idx] = sinf(a);
}

// ---------------------------------------------------------------- GEMM C = A*B^T (A:MxK, B:NxK, bf16)
// Round-3 verified structure: double-buffered LDS + BK=64 (T3 minimal
// 2-phase), ~70us each (was 84). Grid 512 = 2 resident blocks/CU (grid- AND
// 64KB-LDS-capped) — deeper pipelining needs a tile/fusion restructure; kept
// frozen this round. XOR-granule swizzle both-sides (rule #21).
// COMPILE-TIME epilogue flags only — prior-session lesson: runtime-branching
// epilogue flips regalloc to 8-waves/EU target and spills the accumulator.
template<bool ROPE, bool WF32, bool WBF16>
__global__ __launch_bounds__(256) void gemm_bt(
    const unsigned short* __restrict__ A,
    const unsigned short* __restrict__ B,
    float* __restrict__ Cf,
    unsigned short* __restrict__ Cb,
    int M, int N, int K,
    const float* __restrict__ ctab,
    const float* __restrict__ stab,
    float premul)
{
  __shared__ unsigned short As[2][128 * 64];   // 16KB per buf
  __shared__ unsigned short Bs[2][128 * 64];   // total LDS 64KB
  const int tid = threadIdx.x;
  const int wv = tid >> 6;
  const int lane = tid & 63;
  const int q4 = lane >> 4;
  const int l15 = lane & 15;
  const int m0 = blockIdx.y * 128;
  const int n0 = blockIdx.x * 128;
  const int wy = wv >> 1, wx = wv & 1;   // 2x2 waves, 64x64 each

  f32x4 acc[4][4];
  for (int i = 0; i < 4; ++i)
    for (int j = 0; j < 4; ++j)
      acc[i][j] = f32x4{0.f, 0.f, 0.f, 0.f};

  // stage one BK=64 tile pair into buffer `buf`.
  // tile = 128 rows x 8 granules(16B) = 1024 slots; 256 threads x 4 slots.
  // LDS dest is linear in slot (wave-uniform base + lane*16); swizzle lives
  // in the per-lane GLOBAL source granule index.
  auto stage = [&](int buf, int k0) {
    for (int j = 0; j < 4; ++j) {
      int sb = j * 256 + wv * 64;          // wave-uniform slot base
      int slot = sb + lane;
      int row = slot >> 3, cp = slot & 7;
      int c = cp ^ (row & 7);
      gl_lds16(A + (size_t)(m0 + row) * K + k0 + c * 8, &As[buf][sb * 8]);
      gl_lds16(B + (size_t)(n0 + row) * K + k0 + c * 8, &Bs[buf][sb * 8]);
    }
  };

  stage(0, 0);
  __syncthreads();          // implicit vmcnt(0) drain: prologue tile landed

  int cur = 0;
  for (int k0 = 0; k0 < K; k0 += 64) {
    if (k0 + 64 < K) stage(cur ^ 1, k0 + 64);   // prefetch next tile

    short8 af[2][4], bf[2][4];
    for (int s = 0; s < 2; ++s)
      for (int i = 0; i < 4; ++i) {
        int row = wy * 64 + i * 16 + l15;
        int c = (s * 4 + q4) ^ (row & 7);
        af[s][i] = *reinterpret_cast<const short8*>(&As[cur][row * 64 + c * 8]);
      }
    for (int s = 0; s < 2; ++s)
      for (int j = 0; j < 4; ++j) {
        int row = wx * 64 + j * 16 + l15;
        int c = (s * 4 + q4) ^ (row & 7);
        bf[s][j] = *reinterpret_cast<const short8*>(&Bs[cur][row * 64 + c * 8]);
      }
    for (int s = 0; s < 2; ++s)
      for (int i = 0; i < 4; ++i)
        for (int j = 0; j < 4; ++j)
          acc[i][j] = mfma16(af[s][i], bf[s][j], acc[i][j]);

    // one barrier per K-step: drains this iter's prefetch (had the whole MFMA
    // phase to land) and orders LDS reads-done before next iter overwrites.
    __syncthreads();
    cur ^= 1;
  }

  // epilogue: C/D layout col=lane&15, row=(lane>>4)*4+reg (m89-verified)
  for (int i = 0; i < 4; ++i) {
    for (int j = 0; j < 4; ++j) {
      int colb = n0 + wx * 64 + j * 16 + l15;
      for (int r = 0; r < 4; ++r) {
        int row = m0 + wy * 64 + i * 16 + q4 * 4 + r;
        float val = acc[i][j][r];
        if (ROPE) {
          int s = row & (SEQLEN - 1);
          int pi = (colb & (HDIM - 1)) >> 1;
          float cs = ctab[(s << 6) + pi];
          float sn = stab[(s << 6) + pi];
          float partner = __shfl_xor(val, 1);  // adjacent head-dim column = adjacent lane
          val = (colb & 1) ? fmaf(partner, sn, val * cs)
                           : fmaf(val, cs, -partner * sn);
        }
        if (WF32) Cf[(size_t)row * N + colb] = val;
        if (WBF16) Cb[(size_t)row * N + colb] = f2bf(val * premul);
      }
    }
  }
}

// ---------------------------------------------------------------- V (B,S,D) f32 -> Vt (B*H,128,S) bf16
__global__ __launch_bounds__(256) void transpose_v(const float* __restrict__ v,
                                                   unsigned short* __restrict__ vt)
{
  __shared__ float tile[64][65];
  const int b = blockIdx.z;
  const int s0 = blockIdx.y * 64;
  const int d0 = blockIdx.x * 64;
  const int tx = threadIdx.x & 63;
  const int ty = threadIdx.x >> 6;
  for (int r = 0; r < 16; ++r) {
    int srow = r * 4 + ty;
    tile[srow][tx] = v[((size_t)(b * SEQLEN + s0 + srow)) * DIM + d0 + tx];
  }
  __syncthreads();
  for (int r = 0; r < 16; ++r) {
    int drow = r * 4 + ty;
    int d = d0 + drow;
    int bh = b * NHEADS + (d >> 7);
    int dh = d & 127;
    vt[((size_t)(bh * HDIM + dh)) * SEQLEN + s0 + tx] = f2bf(tile[tx][drow]);
  }
}

// ---------------------------------------------------------------- flash attention
// Q-tile 64 (regs, direct from global), KV-tile 64. LDS: K 16KB + Vt 16KB + P 8KB
// = 40KB -> 4 blocks/CU. Grid 1024 blocks, blockIdx.x=bh for XCD-L2 K/V locality.
// VALU-lean softmax (round-1 verified): exp2-space, defer-max THR=8,
// v_cvt_pk_bf16_f32 pack, epilogue l-reduce.
// Round-4: T14 async-STAGE split — rocprof showed 48% of cycles with neither
// MFMA nor VALU issuing = the synchronous gl_lds16 stage + vmcnt(0) barrier
// drain. Now: next tile's K/V loaded to REGISTERS at iter top (latency hides
// under QK+softmax+PV), ds_written to LDS after the tail barrier. Same LDS
// traffic/footprint (40KB, 4 blocks/CU); +32 VGPR. Plus T5 setprio around
// both MFMA clusters (m191: +4-7% attn).
__global__ __launch_bounds__(256, 4) void flash_attn(
    const unsigned short* __restrict__ qb,
    const unsigned short* __restrict__ kb,
    const unsigned short* __restrict__ vt,
    unsigned short* __restrict__ ab)
{
  __shared__ unsigned short KP[64 * 128];   // K tile [key][dh]
  __shared__ unsigned short VTs[128 * 64];  // V tile [dh][key]
  __shared__ unsigned short Ps[64 * 64];    // P tile [q][key]
  const int tid = threadIdx.x;
  const int wvi = tid >> 6;
  const int lane = tid & 63;
  const int q4 = lane >> 4;
  const int l15 = lane & 15;
  const int bh = blockIdx.x;                // fast dim -> XCD = f(bh)
  const int q0 = blockIdx.y * 64;
  const int b = bh >> 4, h = bh & 15;

  const unsigned short* qbase = qb + (size_t)b * SEQLEN * DIM + h * HDIM;
  const unsigned short* kbase = kb + (size_t)b * SEQLEN * DIM + h * HDIM;
  const unsigned short* vbase = vt + (size_t)bh * HDIM * SEQLEN;

  // Q fragments straight from global (A-layout: m=l15 row, k-chunk=ks*4+q4)
  short8 qf[4];
  {
    const unsigned short* qrow = qbase + (size_t)(q0 + wvi * 16 + l15) * DIM;
    for (int ks = 0; ks < 4; ++ks)
      qf[ks] = *reinterpret_cast<const short8*>(qrow + (ks * 4 + q4) * 8);
  }

  float m_run[4], l_run[4];
  f32x4 o[8];
  for (int r = 0; r < 4; ++r) { m_run[r] = -3.0e38f; l_run[r] = 0.f; }
  for (int ct = 0; ct < 8; ++ct) o[ct] = f32x4{0.f, 0.f, 0.f, 0.f};

  const int par = lane & 1;

  // prologue: tile 0 via global_load_lds; the barrier's vmcnt(0) drains it.
  for (int j = 0; j < 4; ++j) {
    int sb = wvi * 256 + j * 64;
    int slot = sb + lane;
    {
      int row = slot >> 4, cp = slot & 15;
      int c = cp ^ (row & 7);
      gl_lds16(kbase + (size_t)row * DIM + c * 8, &KP[sb * 8]);
    }
    {
      int row = slot >> 3, cp = slot & 7;
      int c = cp ^ (row & 7);
      gl_lds16(vbase + (size_t)row * SEQLEN + c * 8, &VTs[sb * 8]);
    }
  }
  __syncthreads();

  for (int kv = 0; kv < SEQLEN / 64; ++kv) {
    // ---- T14 issue-early: next tile's K/V -> registers. Same slot->granule
    // mapping as the gl_lds16 path (LDS linear in slot, swizzle in the global
    // source index), so the late ds_write is a linear conflict-free b128.
    short8 kreg[4], vreg[4];
    const int nkv0 = kv * 64 + 64;
    const bool pre = (kv + 1 < SEQLEN / 64);
    if (pre) {
#pragma unroll
      for (int j = 0; j < 4; ++j) {
        int slot = wvi * 256 + j * 64 + lane;
        int krow = slot >> 4, kc = (slot & 15) ^ (krow & 7);
        kreg[j] = *reinterpret_cast<const short8*>(
            kbase + (size_t)(nkv0 + krow) * DIM + kc * 8);
        int vrow = slot >> 3, vc = (slot & 7) ^ (vrow & 7);
        vreg[j] = *reinterpret_cast<const short8*>(
            vbase + (size_t)vrow * SEQLEN + nkv0 + vc * 8);
      }
    }

    f32x4 sc[4];
    for (int ct = 0; ct < 4; ++ct) sc[ct] = f32x4{0.f, 0.f, 0.f, 0.f};
    __builtin_amdgcn_s_setprio(1);
    for (int ct = 0; ct < 4; ++ct) {
      int kr = ct * 16 + l15;
      for (int ks = 0; ks < 4; ++ks) {
        int c = (ks * 4 + q4) ^ (kr & 7);
        short8 kf = *reinterpret_cast<const short8*>(&KP[kr * 128 + c * 8]);
        sc[ct] = mfma16(qf[ks], kf, sc[ct]);
      }
    }
    __builtin_amdgcn_s_setprio(0);

    // ---- defer-max: cheap per-lane check; full reduce + rescale only on growth
    float lm[4];
    for (int r = 0; r < 4; ++r)
      lm[r] = fmaxf(fmaxf(sc[0][r], sc[1][r]), fmaxf(sc[2][r], sc[3][r]));
    bool grow = false;
    for (int r = 0; r < 4; ++r) grow |= (lm[r] > m_run[r] + 8.0f);
    if (__any(grow)) {
      for (int r = 0; r < 4; ++r) {
        float mx = lm[r];
        for (int d = 1; d < 16; d <<= 1) mx = fmaxf(mx, __shfl_xor(mx, d));
        float mnew = fmaxf(m_run[r], mx);
        float al = __builtin_amdgcn_exp2f(m_run[r] - mnew);
        m_run[r] = mnew;
        l_run[r] *= al;
        for (int ct = 0; ct < 8; ++ct) o[ct][r] *= al;
      }
    }

    // ---- P = exp2(s - m), per-lane partial row-sums (reduced in epilogue)
    for (int ct = 0; ct < 4; ++ct)
      for (int r = 0; r < 4; ++r) {
        float e = __builtin_amdgcn_exp2f(sc[ct][r] - m_run[r]);
        sc[ct][r] = e;
        l_run[r] += e;
      }

    // ---- pack P to bf16 in Ps; each lane packs only the 2 words it writes
    for (int ct = 0; ct < 4; ++ct) {
      float t0 = __shfl_xor(sc[ct][0], 1);
      float t1 = __shfl_xor(sc[ct][1], 1);
      float t2 = __shfl_xor(sc[ct][2], 1);
      float t3 = __shfl_xor(sc[ct][3], 1);
      // par=0 lane writes rows 0,1: lo = own (even col), hi = partner (odd col)
      // par=1 lane writes rows 2,3: lo = partner (even col), hi = own (odd col)
      float a0 = par ? t2 : sc[ct][0];
      float b0 = par ? sc[ct][2] : t0;
      float a1 = par ? t3 : sc[ct][1];
      float b1 = par ? sc[ct][3] : t1;
      unsigned int pk0, pk1;
      asm("v_cvt_pk_bf16_f32 %0, %1, %2" : "=v"(pk0) : "v"(a0), "v"(b0));
      asm("v_cvt_pk_bf16_f32 %0, %1, %2" : "=v"(pk1) : "v"(a1), "v"(b1));
      int col0 = ct * 16 + (l15 & ~1);
      int prow0 = wvi * 16 + q4 * 4 + par * 2;
      int c0 = (col0 >> 3) ^ (prow0 & 7);
      *reinterpret_cast<unsigned int*>(&Ps[prow0 * 64 + c0 * 8 + (col0 & 7)]) = pk0;
      int prow1 = prow0 + 1;
      int c1 = (col0 >> 3) ^ (prow1 & 7);
      *reinterpret_cast<unsigned int*>(&Ps[prow1 * 64 + c1 * 8 + (col0 & 7)]) = pk1;
    }
    __asm__ volatile("s_waitcnt lgkmcnt(0)" ::: "memory");

    short8 pf[2];
    {
      int prow = wvi * 16 + l15;
      for (int ks = 0; ks < 2; ++ks) {
        int c = (ks * 4 + q4) ^ (prow & 7);
        pf[ks] = *reinterpret_cast<const short8*>(&Ps[prow * 64 + c * 8]);
      }
    }
    __builtin_amdgcn_s_setprio(1);
    for (int ct = 0; ct < 8; ++ct) {
      int vr = ct * 16 + l15;
      for (int ks = 0; ks < 2; ++ks) {
        int c = (ks * 4 + q4) ^ (vr & 7);
        short8 vf = *reinterpret_cast<const short8*>(&VTs[vr * 64 + c * 8]);
        o[ct] = mfma16(pf[ks], vf, o[ct]);
      }
    }
    __builtin_amdgcn_s_setprio(0);

    // ---- T14 write-late: all waves done reading tile kv; land tile kv+1.
    __syncthreads();
    if (pre) {
#pragma unroll
      for (int j = 0; j < 4; ++j) {
        int slot = wvi * 256 + j * 64 + lane;
        *reinterpret_cast<short8*>(&KP[slot * 8]) = kreg[j];
        *reinterpret_cast<short8*>(&VTs[slot * 8]) = vreg[j];
      }
    }
    __syncthreads();
  }

  // epilogue: reduce per-lane l partials across the 16-lane row group, then store
  for (int r = 0; r < 4; ++r) {
    float t = l_run[r];
    for (int d = 1; d < 16; d <<= 1) t += __shfl_xor(t, d);
    float invl = 1.0f / t;
    int qrow = q0 + wvi * 16 + q4 * 4 + r;
    size_t base = ((size_t)(b * SEQLEN) + qrow) * DIM + h * HDIM;
    for (int ct = 0; ct < 8; ++ct)
      ab[base + ct * 16 + l15] = f2bf(o[ct][r] * invl);
  }
}

// ---------------------------------------------------------------- launch
extern "C" void kernel_launch(void* const* d_in, const int* in_sizes, int n_in,
                              void* d_out, int out_size, void* d_ws, size_t ws_size,
                              hipStream_t stream) {
  const float* x  = (const float*)d_in[0];
  const float* wq = (const float*)d_in[1];
  const float* wk = (const float*)d_in[2];
  const float* wv = (const float*)d_in[3];
  const float* wo = (const float*)d_in[4];

  float* outp = (float*)d_out;
  float* kout = outp + 8388608;
  float* vout = outp + 16777216;

  unsigned short* ws  = (unsigned short*)d_ws;
  unsigned short* xb  = ws;                   // 8388608
  unsigned short* wqb = xb + 8388608;         // 4194304 each
  unsigned short* wkb = wqb + 4194304;
  unsigned short* wvb = wkb + 4194304;
  unsigned short* wob = wvb + 4194304;
  unsigned short* qb  = wob + 4194304;        // 8388608 (rope'd, pre-scaled)
  unsigned short* kb  = qb + 8388608;         // 8388608 (rope'd)
  unsigned short* vtb = kb + 8388608;         // 8388608 (V^T per head)
  unsigned short* abuf = vtb + 8388608;       // 8388608 (attention out bf16)
  float* ctab = (float*)(abuf + 8388608);     // 131072 f32
  float* stab = ctab + 131072;                // 131072 f32

  cast_all<<<2048, 256, 0, stream>>>(
      (const float4*)x, (const float4*)wq, (const float4*)wk,
      (const float4*)wv, (const float4*)wo,
      (ushort4v*)xb, (ushort4v*)wqb, (ushort4v*)wkb,
      (ushort4v*)wvb, (ushort4v*)wob);
  rope_tables<<<512, 256, 0, stream>>>(ctab, stab);

  dim3 gg(16, 32);  // N/128, M/128
  // 1/sqrt(128) * log2(e): flash softmax runs in exp2-space
  const float qscale = 0.08838834764831845f * 1.4426950408889634f;
  gemm_bt<true,  false, true ><<<gg, 256, 0, stream>>>(xb, wqb, nullptr, qb, 4096, 2048, 2048, ctab, stab, qscale);
  gemm_bt<true,  true,  true ><<<gg, 256, 0, stream>>>(xb, wkb, kout,    kb, 4096, 2048, 2048, ctab, stab, 1.0f);
  gemm_bt<false, true,  false><<<gg, 256, 0, stream>>>(xb, wvb, vout, nullptr, 4096, 2048, 2048, ctab, stab, 1.0f);

  transpose_v<<<dim3(32, 32, 2), 256, 0, stream>>>(vout, vtb);
  flash_attn<<<dim3(32, 32), 256, 0, stream>>>(qb, kb, vtb, abuf);

  gemm_bt<false, true,  false><<<gg, 256, 0, stream>>>(abuf, wob, outp, nullptr, 4096, 2048, 2048, ctab, stab, 1.0f);
}

// Round 5
// 457.562 us; speedup vs baseline: 1.1047x; 1.1047x over previous
//
#include <hip/hip_runtime.h>
#include <hip/hip_bf16.h>

#define DIM 2048
#define SEQLEN 2048
#define NHEADS 16
#define HDIM 128
#define NBATCH 2

using short8 = __attribute__((ext_vector_type(8))) short;
using f32x4 = __attribute__((ext_vector_type(4))) float;
using ushort4v = __attribute__((ext_vector_type(4))) unsigned short;

typedef __attribute__((address_space(1))) const void gvoid_t;
typedef __attribute__((address_space(3))) void lvoid_t;

__device__ __forceinline__ void gl_lds16(const void* g, void* l) {
  __builtin_amdgcn_global_load_lds((gvoid_t*)g, (lvoid_t*)l, 16, 0, 0);
}

__device__ __forceinline__ unsigned short f2bf(float f) {
  union { float f; unsigned int u; } v;
  v.f = f;
  unsigned int u = v.u;
  return (unsigned short)((u + 0x7FFFu + ((u >> 16) & 1u)) >> 16);
}

__device__ __forceinline__ f32x4 mfma16(short8 a, short8 b, f32x4 c) {
  return __builtin_amdgcn_mfma_f32_16x16x32_bf16(a, b, c, 0, 0, 0);
}

// ---------------------------------------------------------------- cast fp32->bf16
__global__ __launch_bounds__(256) void cast_all(
    const float4* __restrict__ x,
    const float4* __restrict__ wq, const float4* __restrict__ wk,
    const float4* __restrict__ wv, const float4* __restrict__ wo,
    ushort4v* __restrict__ xb,
    ushort4v* __restrict__ wqb, ushort4v* __restrict__ wkb,
    ushort4v* __restrict__ wvb, ushort4v* __restrict__ wob)
{
  const long NXV = 2097152;   // 8388608/4
  const long NWV = 1048576;   // 4194304/4
  long tid = (long)blockIdx.x * blockDim.x + threadIdx.x;
  long nth = (long)gridDim.x * blockDim.x;
  for (long i = tid; i < NXV + 4 * NWV; i += nth) {
    const float4* s; ushort4v* dst; long off;
    if (i < NXV) { s = x; dst = xb; off = i; }
    else {
      long j = i - NXV;
      int w = (int)(j >> 20);
      off = j & (NWV - 1);
      switch (w) {
        case 0:  s = wq; dst = wqb; break;
        case 1:  s = wk; dst = wkb; break;
        case 2:  s = wv; dst = wvb; break;
        default: s = wo; dst = wob; break;
      }
    }
    float4 f = s[off];
    ushort4v u;
    u.x = f2bf(f.x); u.y = f2bf(f.y); u.z = f2bf(f.z); u.w = f2bf(f.w);
    dst[off] = u;
  }
}

// ---------------------------------------------------------------- rope cos/sin tables [S][64]
__global__ __launch_bounds__(256) void rope_tables(float* __restrict__ ctab,
                                                   float* __restrict__ stab)
{
  int idx = blockIdx.x * 256 + threadIdx.x;
  if (idx >= SEQLEN * 64) return;
  int s = idx >> 6, i = idx & 63;
  float inv = powf(10000.0f, -(float)(2 * i) * (1.0f / 128.0f));
  float a = (float)s * inv;
  ctab[idx] = cosf(a);
  stab[idx] = sinf(a);
}

// ---------------------------------------------------------------- GEMM C = A*B^T (A:MxK, B:NxK, bf16)
// Round-3 verified structure: double-buffered LDS + BK=64 (T3 minimal
// 2-phase), ~70us each (was 84). Grid 512 = 2 resident blocks/CU (grid- AND
// 64KB-LDS-capped). XOR-granule swizzle both-sides (rule #21). FROZEN.
// COMPILE-TIME epilogue flags only — prior-session lesson: runtime-branching
// epilogue flips regalloc to 8-waves/EU target and spills the accumulator.
template<bool ROPE, bool WF32, bool WBF16>
__global__ __launch_bounds__(256) void gemm_bt(
    const unsigned short* __restrict__ A,
    const unsigned short* __restrict__ B,
    float* __restrict__ Cf,
    unsigned short* __restrict__ Cb,
    int M, int N, int K,
    const float* __restrict__ ctab,
    const float* __restrict__ stab,
    float premul)
{
  __shared__ unsigned short As[2][128 * 64];   // 16KB per buf
  __shared__ unsigned short Bs[2][128 * 64];   // total LDS 64KB
  const int tid = threadIdx.x;
  const int wv = tid >> 6;
  const int lane = tid & 63;
  const int q4 = lane >> 4;
  const int l15 = lane & 15;
  const int m0 = blockIdx.y * 128;
  const int n0 = blockIdx.x * 128;
  const int wy = wv >> 1, wx = wv & 1;   // 2x2 waves, 64x64 each

  f32x4 acc[4][4];
  for (int i = 0; i < 4; ++i)
    for (int j = 0; j < 4; ++j)
      acc[i][j] = f32x4{0.f, 0.f, 0.f, 0.f};

  // stage one BK=64 tile pair into buffer `buf`.
  // tile = 128 rows x 8 granules(16B) = 1024 slots; 256 threads x 4 slots.
  // LDS dest is linear in slot (wave-uniform base + lane*16); swizzle lives
  // in the per-lane GLOBAL source granule index.
  auto stage = [&](int buf, int k0) {
    for (int j = 0; j < 4; ++j) {
      int sb = j * 256 + wv * 64;          // wave-uniform slot base
      int slot = sb + lane;
      int row = slot >> 3, cp = slot & 7;
      int c = cp ^ (row & 7);
      gl_lds16(A + (size_t)(m0 + row) * K + k0 + c * 8, &As[buf][sb * 8]);
      gl_lds16(B + (size_t)(n0 + row) * K + k0 + c * 8, &Bs[buf][sb * 8]);
    }
  };

  stage(0, 0);
  __syncthreads();          // implicit vmcnt(0) drain: prologue tile landed

  int cur = 0;
  for (int k0 = 0; k0 < K; k0 += 64) {
    if (k0 + 64 < K) stage(cur ^ 1, k0 + 64);   // prefetch next tile

    short8 af[2][4], bf[2][4];
    for (int s = 0; s < 2; ++s)
      for (int i = 0; i < 4; ++i) {
        int row = wy * 64 + i * 16 + l15;
        int c = (s * 4 + q4) ^ (row & 7);
        af[s][i] = *reinterpret_cast<const short8*>(&As[cur][row * 64 + c * 8]);
      }
    for (int s = 0; s < 2; ++s)
      for (int j = 0; j < 4; ++j) {
        int row = wx * 64 + j * 16 + l15;
        int c = (s * 4 + q4) ^ (row & 7);
        bf[s][j] = *reinterpret_cast<const short8*>(&Bs[cur][row * 64 + c * 8]);
      }
    for (int s = 0; s < 2; ++s)
      for (int i = 0; i < 4; ++i)
        for (int j = 0; j < 4; ++j)
          acc[i][j] = mfma16(af[s][i], bf[s][j], acc[i][j]);

    // one barrier per K-step: drains this iter's prefetch (had the whole MFMA
    // phase to land) and orders LDS reads-done before next iter overwrites.
    __syncthreads();
    cur ^= 1;
  }

  // epilogue: C/D layout col=lane&15, row=(lane>>4)*4+reg (m89-verified)
  for (int i = 0; i < 4; ++i) {
    for (int j = 0; j < 4; ++j) {
      int colb = n0 + wx * 64 + j * 16 + l15;
      for (int r = 0; r < 4; ++r) {
        int row = m0 + wy * 64 + i * 16 + q4 * 4 + r;
        float val = acc[i][j][r];
        if (ROPE) {
          int s = row & (SEQLEN - 1);
          int pi = (colb & (HDIM - 1)) >> 1;
          float cs = ctab[(s << 6) + pi];
          float sn = stab[(s << 6) + pi];
          float partner = __shfl_xor(val, 1);  // adjacent head-dim column = adjacent lane
          val = (colb & 1) ? fmaf(partner, sn, val * cs)
                           : fmaf(val, cs, -partner * sn);
        }
        if (WF32) Cf[(size_t)row * N + colb] = val;
        if (WBF16) Cb[(size_t)row * N + colb] = f2bf(val * premul);
      }
    }
  }
}

// ---------------------------------------------------------------- V (B,S,D) f32 -> Vt (B*H,128,S) bf16
__global__ __launch_bounds__(256) void transpose_v(const float* __restrict__ v,
                                                   unsigned short* __restrict__ vt)
{
  __shared__ float tile[64][65];
  const int b = blockIdx.z;
  const int s0 = blockIdx.y * 64;
  const int d0 = blockIdx.x * 64;
  const int tx = threadIdx.x & 63;
  const int ty = threadIdx.x >> 6;
  for (int r = 0; r < 16; ++r) {
    int srow = r * 4 + ty;
    tile[srow][tx] = v[((size_t)(b * SEQLEN + s0 + srow)) * DIM + d0 + tx];
  }
  __syncthreads();
  for (int r = 0; r < 16; ++r) {
    int drow = r * 4 + ty;
    int d = d0 + drow;
    int bh = b * NHEADS + (d >> 7);
    int dh = d & 127;
    vt[((size_t)(bh * HDIM + dh)) * SEQLEN + s0 + tx] = f2bf(tile[tx][drow]);
  }
}

// ---------------------------------------------------------------- flash attention
// Round-5: QBLK 128 (8 waves, 512 threads), KV-tile 64. Round-4's reg-staged
// T14 REVERTED: allocator kept its 8-waves/EU target (VGPR stayed 64) and
// spilled the prefetch arrays to scratch (WRITE_SIZE 16->40MB, +38us).
// Instead, halve the stage-to-compute ratio structurally: K/V staged once per
// block now feeds 128 Q rows instead of 64, so the stage+vmcnt(0)-drain
// bubble (the ~48% dual-idle rocprof showed in round 3) amortizes over 2x
// MFMA work, with ZERO new per-thread live state (no spill trap).
// LDS: K 16KB + Vt 16KB + P 16KB = 48KB. Grid 32x16 = 512 blocks = 2/CU x 8
// waves = 16 waves/CU (same occupancy as round-3's 4x4). Per-wave code
// identical to round-3 (exp2-space, defer-max THR=8, cvt_pk pack, epilogue
// l-reduce); only wvi now spans 0..7 and Ps has 128 rows.
__global__ __launch_bounds__(512, 4) void flash_attn(
    const unsigned short* __restrict__ qb,
    const unsigned short* __restrict__ kb,
    const unsigned short* __restrict__ vt,
    unsigned short* __restrict__ ab)
{
  __shared__ unsigned short KP[64 * 128];    // K tile [key][dh]
  __shared__ unsigned short VTs[128 * 64];   // V tile [dh][key]
  __shared__ unsigned short Ps[128 * 64];    // P tile [q][key]
  const int tid = threadIdx.x;
  const int wvi = tid >> 6;                  // 0..7
  const int lane = tid & 63;
  const int q4 = lane >> 4;
  const int l15 = lane & 15;
  const int bh = blockIdx.x;                 // fast dim -> XCD = f(bh)
  const int q0 = blockIdx.y * 128;
  const int b = bh >> 4, h = bh & 15;

  const unsigned short* qbase = qb + (size_t)b * SEQLEN * DIM + h * HDIM;
  const unsigned short* kbase = kb + (size_t)b * SEQLEN * DIM + h * HDIM;
  const unsigned short* vbase = vt + (size_t)bh * HDIM * SEQLEN;

  // Q fragments straight from global (A-layout: m=l15 row, k-chunk=ks*4+q4)
  short8 qf[4];
  {
    const unsigned short* qrow = qbase + (size_t)(q0 + wvi * 16 + l15) * DIM;
    for (int ks = 0; ks < 4; ++ks)
      qf[ks] = *reinterpret_cast<const short8*>(qrow + (ks * 4 + q4) * 8);
  }

  float m_run[4], l_run[4];
  f32x4 o[8];
  for (int r = 0; r < 4; ++r) { m_run[r] = -3.0e38f; l_run[r] = 0.f; }
  for (int ct = 0; ct < 8; ++ct) o[ct] = f32x4{0.f, 0.f, 0.f, 0.f};

  const int par = lane & 1;

  for (int kv = 0; kv < SEQLEN / 64; ++kv) {
    const int kv0 = kv * 64;
    // stage K (1024 granules) + V (1024 granules); 512 threads x 2 each.
    for (int j = 0; j < 2; ++j) {
      int sb = wvi * 128 + j * 64;           // wave-uniform slot base
      int slot = sb + lane;
      {
        int row = slot >> 4, cp = slot & 15;
        int c = cp ^ (row & 7);
        gl_lds16(kbase + (size_t)(kv0 + row) * DIM + c * 8, &KP[sb * 8]);
      }
      {
        int row = slot >> 3, cp = slot & 7;
        int c = cp ^ (row & 7);
        gl_lds16(vbase + (size_t)row * SEQLEN + kv0 + c * 8, &VTs[sb * 8]);
      }
    }
    __syncthreads();

    f32x4 sc[4];
    for (int ct = 0; ct < 4; ++ct) sc[ct] = f32x4{0.f, 0.f, 0.f, 0.f};
    for (int ct = 0; ct < 4; ++ct) {
      int kr = ct * 16 + l15;
      for (int ks = 0; ks < 4; ++ks) {
        int c = (ks * 4 + q4) ^ (kr & 7);
        short8 kf = *reinterpret_cast<const short8*>(&KP[kr * 128 + c * 8]);
        sc[ct] = mfma16(qf[ks], kf, sc[ct]);
      }
    }

    // ---- defer-max: cheap per-lane check; full reduce + rescale only on growth
    float lm[4];
    for (int r = 0; r < 4; ++r)
      lm[r] = fmaxf(fmaxf(sc[0][r], sc[1][r]), fmaxf(sc[2][r], sc[3][r]));
    bool grow = false;
    for (int r = 0; r < 4; ++r) grow |= (lm[r] > m_run[r] + 8.0f);
    if (__any(grow)) {
      for (int r = 0; r < 4; ++r) {
        float mx = lm[r];
        for (int d = 1; d < 16; d <<= 1) mx = fmaxf(mx, __shfl_xor(mx, d));
        float mnew = fmaxf(m_run[r], mx);
        float al = __builtin_amdgcn_exp2f(m_run[r] - mnew);
        m_run[r] = mnew;
        l_run[r] *= al;
        for (int ct = 0; ct < 8; ++ct) o[ct][r] *= al;
      }
    }

    // ---- P = exp2(s - m), per-lane partial row-sums (reduced in epilogue)
    for (int ct = 0; ct < 4; ++ct)
      for (int r = 0; r < 4; ++r) {
        float e = __builtin_amdgcn_exp2f(sc[ct][r] - m_run[r]);
        sc[ct][r] = e;
        l_run[r] += e;
      }

    // ---- pack P to bf16 in Ps; each lane packs only the 2 words it writes
    for (int ct = 0; ct < 4; ++ct) {
      float t0 = __shfl_xor(sc[ct][0], 1);
      float t1 = __shfl_xor(sc[ct][1], 1);
      float t2 = __shfl_xor(sc[ct][2], 1);
      float t3 = __shfl_xor(sc[ct][3], 1);
      // par=0 lane writes rows 0,1: lo = own (even col), hi = partner (odd col)
      // par=1 lane writes rows 2,3: lo = partner (even col), hi = own (odd col)
      float a0 = par ? t2 : sc[ct][0];
      float b0 = par ? sc[ct][2] : t0;
      float a1 = par ? t3 : sc[ct][1];
      float b1 = par ? sc[ct][3] : t1;
      unsigned int pk0, pk1;
      asm("v_cvt_pk_bf16_f32 %0, %1, %2" : "=v"(pk0) : "v"(a0), "v"(b0));
      asm("v_cvt_pk_bf16_f32 %0, %1, %2" : "=v"(pk1) : "v"(a1), "v"(b1));
      int col0 = ct * 16 + (l15 & ~1);
      int prow0 = wvi * 16 + q4 * 4 + par * 2;
      int c0 = (col0 >> 3) ^ (prow0 & 7);
      *reinterpret_cast<unsigned int*>(&Ps[prow0 * 64 + c0 * 8 + (col0 & 7)]) = pk0;
      int prow1 = prow0 + 1;
      int c1 = (col0 >> 3) ^ (prow1 & 7);
      *reinterpret_cast<unsigned int*>(&Ps[prow1 * 64 + c1 * 8 + (col0 & 7)]) = pk1;
    }
    __asm__ volatile("s_waitcnt lgkmcnt(0)" ::: "memory");

    short8 pf[2];
    {
      int prow = wvi * 16 + l15;
      for (int ks = 0; ks < 2; ++ks) {
        int c = (ks * 4 + q4) ^ (prow & 7);
        pf[ks] = *reinterpret_cast<const short8*>(&Ps[prow * 64 + c * 8]);
      }
    }
    for (int ct = 0; ct < 8; ++ct) {
      int vr = ct * 16 + l15;
      for (int ks = 0; ks < 2; ++ks) {
        int c = (ks * 4 + q4) ^ (vr & 7);
        short8 vf = *reinterpret_cast<const short8*>(&VTs[vr * 64 + c * 8]);
        o[ct] = mfma16(pf[ks], vf, o[ct]);
      }
    }
    __syncthreads();
  }

  // epilogue: reduce per-lane l partials across the 16-lane row group, then store
  for (int r = 0; r < 4; ++r) {
    float t = l_run[r];
    for (int d = 1; d < 16; d <<= 1) t += __shfl_xor(t, d);
    float invl = 1.0f / t;
    int qrow = q0 + wvi * 16 + q4 * 4 + r;
    size_t base = ((size_t)(b * SEQLEN) + qrow) * DIM + h * HDIM;
    for (int ct = 0; ct < 8; ++ct)
      ab[base + ct * 16 + l15] = f2bf(o[ct][r] * invl);
  }
}

// ---------------------------------------------------------------- launch
extern "C" void kernel_launch(void* const* d_in, const int* in_sizes, int n_in,
                              void* d_out, int out_size, void* d_ws, size_t ws_size,
                              hipStream_t stream) {
  const float* x  = (const float*)d_in[0];
  const float* wq = (const float*)d_in[1];
  const float* wk = (const float*)d_in[2];
  const float* wv = (const float*)d_in[3];
  const float* wo = (const float*)d_in[4];

  float* outp = (float*)d_out;
  float* kout = outp + 8388608;
  float* vout = outp + 16777216;

  unsigned short* ws  = (unsigned short*)d_ws;
  unsigned short* xb  = ws;                   // 8388608
  unsigned short* wqb = xb + 8388608;         // 4194304 each
  unsigned short* wkb = wqb + 4194304;
  unsigned short* wvb = wkb + 4194304;
  unsigned short* wob = wvb + 4194304;
  unsigned short* qb  = wob + 4194304;        // 8388608 (rope'd, pre-scaled)
  unsigned short* kb  = qb + 8388608;         // 8388608 (rope'd)
  unsigned short* vtb = kb + 8388608;         // 8388608 (V^T per head)
  unsigned short* abuf = vtb + 8388608;       // 8388608 (attention out bf16)
  float* ctab = (float*)(abuf + 8388608);     // 131072 f32
  float* stab = ctab + 131072;                // 131072 f32

  cast_all<<<2048, 256, 0, stream>>>(
      (const float4*)x, (const float4*)wq, (const float4*)wk,
      (const float4*)wv, (const float4*)wo,
      (ushort4v*)xb, (ushort4v*)wqb, (ushort4v*)wkb,
      (ushort4v*)wvb, (ushort4v*)wob);
  rope_tables<<<512, 256, 0, stream>>>(ctab, stab);

  dim3 gg(16, 32);  // N/128, M/128
  // 1/sqrt(128) * log2(e): flash softmax runs in exp2-space
  const float qscale = 0.08838834764831845f * 1.4426950408889634f;
  gemm_bt<true,  false, true ><<<gg, 256, 0, stream>>>(xb, wqb, nullptr, qb, 4096, 2048, 2048, ctab, stab, qscale);
  gemm_bt<true,  true,  true ><<<gg, 256, 0, stream>>>(xb, wkb, kout,    kb, 4096, 2048, 2048, ctab, stab, 1.0f);
  gemm_bt<false, true,  false><<<gg, 256, 0, stream>>>(xb, wvb, vout, nullptr, 4096, 2048, 2048, ctab, stab, 1.0f);

  transpose_v<<<dim3(32, 32, 2), 256, 0, stream>>>(vout, vtb);
  flash_attn<<<dim3(32, 16), 512, 0, stream>>>(qb, kb, vtb, abuf);

  gemm_bt<false, true,  false><<<gg, 256, 0, stream>>>(abuf, wob, outp, nullptr, 4096, 2048, 2048, ctab, stab, 1.0f);
}